// Round 24
// baseline (53.806 us; speedup 1.0000x reference)
//
#include <hip/hip_runtime.h>
#include <math.h>

#define BB 2
#define SS 192
#define DD 512
#define HH 8
#define HD 64
#define QCB 6                 // q-rows per block
#define NQC (SS / QCB)        // 32 q-chunks
#define PROJ_N (BB*HH*SS*HD)
#define KLPAD (8 * 193 * 8)   // padded frag-major plane per bh: 12352 shorts
#define SCL (0.125f * 1.44269504088896f)   // 1/sqrt(64) * log2(e)

typedef __attribute__((ext_vector_type(4))) float f32x4;
typedef _Float16 f16x8 __attribute__((ext_vector_type(8)));

// 8 f32 -> f16x8, RNE (v_cvt_f16_f32)
__device__ __forceinline__ f16x8 cvt8_f16_rne(const float* g) {
    f16x8 r;
#pragma unroll
    for (int i = 0; i < 8; ++i) r[i] = (_Float16)g[i];
    return r;
}
__device__ __forceinline__ short f16s(float v) {
    return __builtin_bit_cast(short, (_Float16)v);
}

// ---------------------------------------------------------------------------
// Split-K projection GEMM (R22, unchanged): 512 thr = 2 teams x 256; team tau
// covers K in [256*tau, +256) in 4 BK=64 rounds; teams combine via LDS.
// Epilogue stores f16 in consumer layout. Prologue zeroes `out`.
// ---------------------------------------------------------------------------
__global__ __launch_bounds__(512) void proj4_kernel(
    const float* __restrict__ xq, const float* __restrict__ xk,
    const float* __restrict__ xl, const float* __restrict__ xv,
    const float* __restrict__ Wq, const float* __restrict__ Wk,
    const float* __restrict__ Wv, float* __restrict__ vhp,
    short* __restrict__ qf16, short* __restrict__ khf16,
    short* __restrict__ lhf16, float* __restrict__ out) {
    const int p = blockIdx.z;
    const float* x = (p == 0) ? xq : (p == 1) ? xk : (p == 2) ? xl : xv;
    const float* W = (p == 0) ? Wq : (p == 3) ? Wv : Wk;

    __shared__ short Ahs[2][2][8 * 64 * 8];   // [team][buf][ec][row][8]: 32 KB
    __shared__ short Bhs[2][2][8 * 64 * 8];   // 32 KB
    __shared__ float accs[64][65];            // team-1 partial: 16.6 KB

    const int t = threadIdx.x;

    // zero `out`: 192 blocks x 512 thr
    {
        const int bid = (blockIdx.z * gridDim.y + blockIdx.y) * gridDim.x + blockIdx.x;
        for (int i = bid * 512 + t; i < BB * SS * DD; i += 192 * 512) out[i] = 0.f;
    }

    const int team = t >> 8, tt = t & 255;
    const int lane = tt & 63, w4 = tt >> 6;
    const int wr = w4 >> 1, wc = w4 & 1;
    const int c16 = lane & 15, q4 = lane >> 4;
    const int m0 = blockIdx.x * 64, n0 = blockIdx.y * 64;
    const int r = tt >> 2, cc = tt & 3;   // staging: row 0..63, quarter 0..3
    const int kbase = team * 256;

    f32x4 acc[2][2];
#pragma unroll
    for (int a = 0; a < 2; ++a)
#pragma unroll
        for (int b = 0; b < 2; ++b) acc[a][b] = (f32x4){0.f, 0.f, 0.f, 0.f};

#define STAGE(kk, bf)                                                               \
    {                                                                               \
        _Pragma("unroll") for (int h2 = 0; h2 < 2; ++h2) {                          \
            const int ec = cc * 2 + h2;                                             \
            float a8[8], w8[8];                                                     \
            *(f32x4*)&a8[0] = *(const f32x4*)&x[(m0 + r) * 512 + (kk) + ec * 8];    \
            *(f32x4*)&a8[4] = *(const f32x4*)&x[(m0 + r) * 512 + (kk) + ec * 8 + 4];\
            *(f32x4*)&w8[0] = *(const f32x4*)&W[(n0 + r) * 512 + (kk) + ec * 8];    \
            *(f32x4*)&w8[4] = *(const f32x4*)&W[(n0 + r) * 512 + (kk) + ec * 8 + 4];\
            *(f16x8*)&Ahs[team][bf][(ec * 64 + r) * 8] = cvt8_f16_rne(a8);          \
            *(f16x8*)&Bhs[team][bf][(ec * 64 + r) * 8] = cvt8_f16_rne(w8);          \
        }                                                                           \
    }

    STAGE(kbase, 0)
    for (int s = 0; s < 4; ++s) {
        __syncthreads();
        if (s + 1 < 4) STAGE(kbase + (s + 1) * 64, (s + 1) & 1)
        const int b = s & 1;
        f16x8 aH[2][2], bH[2][2];
#pragma unroll
        for (int mt = 0; mt < 2; ++mt) {
            const int row = wr * 32 + mt * 16 + c16;
            aH[mt][0] = *(const f16x8*)&Ahs[team][b][(q4 * 64 + row) * 8];
            aH[mt][1] = *(const f16x8*)&Ahs[team][b][((q4 + 4) * 64 + row) * 8];
        }
#pragma unroll
        for (int nt = 0; nt < 2; ++nt) {
            const int col = wc * 32 + nt * 16 + c16;
            bH[nt][0] = *(const f16x8*)&Bhs[team][b][(q4 * 64 + col) * 8];
            bH[nt][1] = *(const f16x8*)&Bhs[team][b][((q4 + 4) * 64 + col) * 8];
        }
#pragma unroll
        for (int mt = 0; mt < 2; ++mt)
#pragma unroll
            for (int nt = 0; nt < 2; ++nt) {
                acc[mt][nt] = __builtin_amdgcn_mfma_f32_16x16x32_f16(aH[mt][0], bH[nt][0], acc[mt][nt], 0, 0, 0);
                acc[mt][nt] = __builtin_amdgcn_mfma_f32_16x16x32_f16(aH[mt][1], bH[nt][1], acc[mt][nt], 0, 0, 0);
            }
    }
#undef STAGE

    if (team == 1) {
#pragma unroll
        for (int mt = 0; mt < 2; ++mt)
#pragma unroll
            for (int nt = 0; nt < 2; ++nt)
#pragma unroll
                for (int j = 0; j < 4; ++j) {
                    const int row = wr * 32 + mt * 16 + q4 * 4 + j;
                    const int col = wc * 32 + nt * 16 + c16;
                    accs[row][col] = acc[mt][nt][j];
                }
    }
    __syncthreads();
    if (team == 0) {
#pragma unroll
        for (int mt = 0; mt < 2; ++mt)
#pragma unroll
            for (int nt = 0; nt < 2; ++nt)
#pragma unroll
                for (int j = 0; j < 4; ++j) {
                    const int row = wr * 32 + mt * 16 + q4 * 4 + j;
                    const int col = wc * 32 + nt * 16 + c16;
                    const float v = acc[mt][nt][j] + accs[row][col];
                    const int n_row = m0 + row;
                    const int jcol = n0 + col;
                    const int b = n_row / SS, s2 = n_row % SS;
                    const int h = jcol >> 6, e = jcol & 63;
                    const int bh = b * HH + h;
                    if (p == 3) {
                        vhp[(bh * SS + s2) * HD + e] = v;
                    } else if (p == 0) {
                        qf16[(bh * SS + s2) * HD + e] = f16s(v * SCL);
                    } else {
                        short* dst = (p == 1) ? khf16 : lhf16;
                        dst[bh * KLPAD + (e >> 3) * (193 * 8) + s2 * 8 + (e & 7)] = f16s(v);
                    }
                }
    }
}

// ---------------------------------------------------------------------------
// MFMA rank-3 attention, 1024-thr blocks (16 waves: 4 lg x 4 kg).
// Grid 512 = 16 bh x 32 qc (QCB=6), SAME grid/staging as R22 -- but each
// wave covers 48 l x 48 k (half of R22's work) and 32 waves/CU co-reside
// (2 blocks x 16 waves; LDS 55 KB/block, natural VGPR ~64 = 8/SIMD class).
// Single-q core (rotated), eh==0 ds_add into Wt (4-way), attd unions dead
// K-space. Fused Wout MFMA epilogue (16 waves x 2 j-tiles).
// ---------------------------------------------------------------------------
__global__ __launch_bounds__(1024) void attn3d_mfma_kernel(
    const short* __restrict__ qf16, const short* __restrict__ khf16,
    const short* __restrict__ lhf16, const float* __restrict__ vh,
    const float* __restrict__ Wout, float* __restrict__ out) {
    __shared__ short Kf16[8][193][8];       // 24.1 KB (attd reuses after q loop)
    __shared__ short Lf16[8][193][8];       // 24.1 KB
    __shared__ short qpk[QCB][8][8];        // 768 B
    __shared__ float Wt[QCB][192];          // 4.6 KB (ds_add accumulated)
    __shared__ float zinv[QCB];
    float (*attd)[72] = (float(*)[72]) & Kf16[0][0][0];  // 4.5 KB, K-space

    const int blk = blockIdx.x;
    const int bh = blk >> 5, qc = blk & 31;
    const int t = threadIdx.x;
    const int lane = t & 63, w = t >> 6;   // w in [0,16)
    const int lg = w >> 2, kg = w & 3;     // 4 x 4
    const int c = lane & 15, eh = lane >> 4;

    // ---- zero Wt (ds_add target) ----
    for (int id = t; id < QCB * 192; id += 1024) ((float*)Wt)[id] = 0.f;
    // ---- stage q rows (pre-scaled f16): 48 x 16B copies ----
    if (t < QCB * 8) {
        const int q = t >> 3, ecj = t & 7;
        *(f16x8*)&qpk[q][ecj][0] =
            *(const f16x8*)&qf16[(bh * SS + qc * QCB + q) * HD + ecj * 8];
    }
    // ---- stage K and L: pure 16B copies (1536 chunks over 1024 thr) ----
#pragma unroll
    for (int j = 0; j < 2; ++j) {
        const int cid = t + 1024 * j;
        if (cid < 1536) {
            const int ec = cid / 192, k2 = cid - ec * 192;
            const int off = ec * (193 * 8) + k2 * 8;
            *(f16x8*)&(((short*)Kf16)[off]) = *(const f16x8*)&khf16[bh * KLPAD + off];
            *(f16x8*)&(((short*)Lf16)[off]) = *(const f16x8*)&lhf16[bh * KLPAD + off];
        }
    }
    __syncthreads();   // Wt zeroed; qpk, Kf16, Lf16 ready

    // ---- single-q loop, rotated per wave; B hoisted per q ----
    for (int qi = 0; qi < QCB; ++qi) {
        const int q = (qi + w) % QCB;
        const f16x8 qf0 = *(const f16x8*)&qpk[q][eh][0];
        const f16x8 qf1 = *(const f16x8*)&qpk[q][4 + eh][0];
        f16x8 Bf[3][2];
#pragma unroll
        for (int kt = 0; kt < 3; ++kt) {
            const int col = kg * 48 + kt * 16 + c;
            Bf[kt][0] = *(const f16x8*)&Kf16[eh][col][0] * qf0;
            Bf[kt][1] = *(const f16x8*)&Kf16[4 + eh][col][0] * qf1;
        }
        float rr0 = 0.f, rr1 = 0.f, rr2 = 0.f;
#pragma unroll
        for (int lt = 0; lt < 3; ++lt) {
            const int row = lg * 48 + lt * 16 + c;
            const f16x8 A0 = *(const f16x8*)&Lf16[eh][row][0];
            const f16x8 A1 = *(const f16x8*)&Lf16[4 + eh][row][0];
            f32x4 a0 = (f32x4){0.f, 0.f, 0.f, 0.f};
            f32x4 a1 = (f32x4){0.f, 0.f, 0.f, 0.f};
            f32x4 a2 = (f32x4){0.f, 0.f, 0.f, 0.f};
            a0 = __builtin_amdgcn_mfma_f32_16x16x32_f16(A0, Bf[0][0], a0, 0, 0, 0);
            a1 = __builtin_amdgcn_mfma_f32_16x16x32_f16(A0, Bf[1][0], a1, 0, 0, 0);
            a2 = __builtin_amdgcn_mfma_f32_16x16x32_f16(A0, Bf[2][0], a2, 0, 0, 0);
            a0 = __builtin_amdgcn_mfma_f32_16x16x32_f16(A1, Bf[0][1], a0, 0, 0, 0);
            a1 = __builtin_amdgcn_mfma_f32_16x16x32_f16(A1, Bf[1][1], a1, 0, 0, 0);
            a2 = __builtin_amdgcn_mfma_f32_16x16x32_f16(A1, Bf[2][1], a2, 0, 0, 0);
            rr0 += (__builtin_amdgcn_exp2f(a0[0]) + __builtin_amdgcn_exp2f(a0[1])) +
                   (__builtin_amdgcn_exp2f(a0[2]) + __builtin_amdgcn_exp2f(a0[3]));
            rr1 += (__builtin_amdgcn_exp2f(a1[0]) + __builtin_amdgcn_exp2f(a1[1])) +
                   (__builtin_amdgcn_exp2f(a1[2]) + __builtin_amdgcn_exp2f(a1[3]));
            rr2 += (__builtin_amdgcn_exp2f(a2[0]) + __builtin_amdgcn_exp2f(a2[1])) +
                   (__builtin_amdgcn_exp2f(a2[2]) + __builtin_amdgcn_exp2f(a2[3]));
        }
        rr0 += __shfl_xor(rr0, 16, 64);
        rr1 += __shfl_xor(rr1, 16, 64);
        rr2 += __shfl_xor(rr2, 16, 64);
        rr0 += __shfl_xor(rr0, 32, 64);
        rr1 += __shfl_xor(rr1, 32, 64);
        rr2 += __shfl_xor(rr2, 32, 64);
        if (eh == 0) {
            atomicAdd(&Wt[q][kg * 48 + 0 * 16 + c], rr0);   // ds_add_f32, 4-way
            atomicAdd(&Wt[q][kg * 48 + 1 * 16 + c], rr1);
            atomicAdd(&Wt[q][kg * 48 + 2 * 16 + c], rr2);
        }
    }
    __syncthreads();   // Wt complete; Kf16 now dead -> attd space free

    // Z per q (wave w handles q = w); concurrently zero attd (K-space)
    if (w < QCB) {
        const int q = w;
        float z = Wt[q][lane] + Wt[q][lane + 64] + Wt[q][lane + 128];
#pragma unroll
        for (int off = 32; off >= 1; off >>= 1) z += __shfl_xor(z, off, 64);
        if (lane == 0) zinv[q] = 1.f / z;
    }
    for (int id = t; id < 16 * 72; id += 1024) ((float*)attd)[id] = 0.f;
    __syncthreads();

    // attended -> attd LDS: attd[q][d] = zinv * sum_k Wt[q][k] * vh[k,d]
    if (t < QCB * 64) {
        const int q = t >> 6, d = t & 63;
        const float* vp = vh + bh * SS * HD + d;
        float sum = 0.f;
        for (int k0 = 0; k0 < SS; k0 += 8) {
            float v8[8];
#pragma unroll
            for (int j = 0; j < 8; ++j) v8[j] = vp[(k0 + j) * HD];
#pragma unroll
            for (int j = 0; j < 8; ++j) sum = fmaf(Wt[q][k0 + j], v8[j], sum);
        }
        attd[q][d] = sum * zinv[q];
    }
    __syncthreads();

    // ---- fused output projection: out[q,:] += attd . Wout[:, h*64:+64]^T ----
    const int b = bh >> 3, h = bh & 7;
    f16x8 Ae0, Ae1;
    {
        float a8[8];
        *(f32x4*)&a8[0] = *(const f32x4*)&attd[c][eh * 8];
        *(f32x4*)&a8[4] = *(const f32x4*)&attd[c][eh * 8 + 4];
        Ae0 = cvt8_f16_rne(a8);
        *(f32x4*)&a8[0] = *(const f32x4*)&attd[c][32 + eh * 8];
        *(f32x4*)&a8[4] = *(const f32x4*)&attd[c][32 + eh * 8 + 4];
        Ae1 = cvt8_f16_rne(a8);
    }
#pragma unroll
    for (int jt = 0; jt < 2; ++jt) {
        const int j = (w * 2 + jt) * 16 + c;
        const float* wp = &Wout[j * DD + h * HD];
        float b8[8];
        *(f32x4*)&b8[0] = *(const f32x4*)&wp[eh * 8];
        *(f32x4*)&b8[4] = *(const f32x4*)&wp[eh * 8 + 4];
        const f16x8 B0 = cvt8_f16_rne(b8);
        *(f32x4*)&b8[0] = *(const f32x4*)&wp[32 + eh * 8];
        *(f32x4*)&b8[4] = *(const f32x4*)&wp[32 + eh * 8 + 4];
        const f16x8 B1 = cvt8_f16_rne(b8);
        f32x4 oc = (f32x4){0.f, 0.f, 0.f, 0.f};
        oc = __builtin_amdgcn_mfma_f32_16x16x32_f16(Ae0, B0, oc, 0, 0, 0);
        oc = __builtin_amdgcn_mfma_f32_16x16x32_f16(Ae1, B1, oc, 0, 0, 0);
#pragma unroll
        for (int jj = 0; jj < 4; ++jj) {
            const int q = eh * 4 + jj;
            if (q < QCB)
                atomicAdd(&out[(b * SS + qc * QCB + q) * DD + (w * 2 + jt) * 16 + c], oc[jj]);
        }
    }
}

extern "C" void kernel_launch(void* const* d_in, const int* in_sizes, int n_in,
                              void* d_out, int out_size, void* d_ws, size_t ws_size,
                              hipStream_t stream) {
    (void)in_sizes; (void)n_in; (void)out_size; (void)ws_size;
    const float* q    = (const float*)d_in[0];
    const float* k    = (const float*)d_in[1];
    const float* l    = (const float*)d_in[2];
    const float* v    = (const float*)d_in[3];
    const float* Wq   = (const float*)d_in[4];
    const float* Wk   = (const float*)d_in[5];
    const float* Wv   = (const float*)d_in[6];
    const float* Wout = (const float*)d_in[7];
    float* out = (float*)d_out;

    float* ws    = (float*)d_ws;
    float* vhp   = ws;                                   // PROJ_N f32
    short* qf16  = (short*)(ws + PROJ_N);                // PROJ_N f16
    short* khf16 = qf16 + PROJ_N;                        // 16*KLPAD f16 (padded)
    short* lhf16 = khf16 + 16 * KLPAD;                   // 16*KLPAD f16

    // projections (split-K teams, f16 outputs pre-laid-out) + out-zero prologue
    proj4_kernel<<<dim3(384 / 64, 512 / 64, 4), 512, 0, stream>>>(
        q, k, l, v, Wq, Wk, Wv, vhp, qf16, khf16, lhf16, out);
    // rank-3 attention (1024-thr blocks, 32 waves/CU) + fused output projection
    attn3d_mfma_kernel<<<dim3(16 * NQC), 1024, 0, stream>>>(
        qf16, khf16, lhf16, vhp, Wout, out);
}

// Round 25
// 41.877 us; speedup vs baseline: 1.2849x; 1.2849x over previous
//
#include <hip/hip_runtime.h>
#include <math.h>

#define BB 2
#define SS 192
#define DD 512
#define HH 8
#define HD 64
#define QCB 6                 // q-rows per block
#define NQC (SS / QCB)        // 32 q-chunks
#define PROJ_N (BB*HH*SS*HD)
#define KLPAD (8 * 193 * 8)   // padded frag-major plane per bh: 12352 shorts
#define SCL (0.125f * 1.44269504088896f)   // 1/sqrt(64) * log2(e)

typedef __attribute__((ext_vector_type(4))) float f32x4;
typedef _Float16 f16x8 __attribute__((ext_vector_type(8)));

// 8 f32 -> f16x8, RNE (v_cvt_f16_f32)
__device__ __forceinline__ f16x8 cvt8_f16_rne(const float* g) {
    f16x8 r;
#pragma unroll
    for (int i = 0; i < 8; ++i) r[i] = (_Float16)g[i];
    return r;
}
__device__ __forceinline__ short f16s(float v) {
    return __builtin_bit_cast(short, (_Float16)v);
}

// ---------------------------------------------------------------------------
// Split-K projection GEMM: 512 thr = 2 teams x 256; team tau covers
// K in [256*tau, 256*tau+256) in 4 BK=64 rounds. Teams combine via LDS accs
// (team1 write, barrier, team0 add) -- plain stores, no atomics. Epilogue
// stores f16 in consumer layout:
//   p=0 Q: row-major f16, SCL pre-folded
//   p=1/2 K/L: padded frag-major f16 [bh][ec][k(+pad193)][8]
//   p=3 V: f32 head-split
// Prologue zeroes `out` (attn's atomic target; stream-ordered).
// ---------------------------------------------------------------------------
__global__ __launch_bounds__(512) void proj4_kernel(
    const float* __restrict__ xq, const float* __restrict__ xk,
    const float* __restrict__ xl, const float* __restrict__ xv,
    const float* __restrict__ Wq, const float* __restrict__ Wk,
    const float* __restrict__ Wv, float* __restrict__ vhp,
    short* __restrict__ qf16, short* __restrict__ khf16,
    short* __restrict__ lhf16, float* __restrict__ out) {
    const int p = blockIdx.z;
    const float* x = (p == 0) ? xq : (p == 1) ? xk : (p == 2) ? xl : xv;
    const float* W = (p == 0) ? Wq : (p == 3) ? Wv : Wk;

    __shared__ short Ahs[2][2][8 * 64 * 8];   // [team][buf][ec][row][8]: 32 KB
    __shared__ short Bhs[2][2][8 * 64 * 8];   // 32 KB
    __shared__ float accs[64][65];            // team-1 partial: 16.6 KB

    const int t = threadIdx.x;

    // zero `out`: 192 blocks x 512 thr
    {
        const int bid = (blockIdx.z * gridDim.y + blockIdx.y) * gridDim.x + blockIdx.x;
        for (int i = bid * 512 + t; i < BB * SS * DD; i += 192 * 512) out[i] = 0.f;
    }

    const int team = t >> 8, tt = t & 255;
    const int lane = tt & 63, w4 = tt >> 6;
    const int wr = w4 >> 1, wc = w4 & 1;
    const int c16 = lane & 15, q4 = lane >> 4;
    const int m0 = blockIdx.x * 64, n0 = blockIdx.y * 64;
    const int r = tt >> 2, cc = tt & 3;   // staging: row 0..63, quarter 0..3
    const int kbase = team * 256;

    f32x4 acc[2][2];
#pragma unroll
    for (int a = 0; a < 2; ++a)
#pragma unroll
        for (int b = 0; b < 2; ++b) acc[a][b] = (f32x4){0.f, 0.f, 0.f, 0.f};

#define STAGE(kk, bf)                                                               \
    {                                                                               \
        _Pragma("unroll") for (int h2 = 0; h2 < 2; ++h2) {                          \
            const int ec = cc * 2 + h2;                                             \
            float a8[8], w8[8];                                                     \
            *(f32x4*)&a8[0] = *(const f32x4*)&x[(m0 + r) * 512 + (kk) + ec * 8];    \
            *(f32x4*)&a8[4] = *(const f32x4*)&x[(m0 + r) * 512 + (kk) + ec * 8 + 4];\
            *(f32x4*)&w8[0] = *(const f32x4*)&W[(n0 + r) * 512 + (kk) + ec * 8];    \
            *(f32x4*)&w8[4] = *(const f32x4*)&W[(n0 + r) * 512 + (kk) + ec * 8 + 4];\
            *(f16x8*)&Ahs[team][bf][(ec * 64 + r) * 8] = cvt8_f16_rne(a8);          \
            *(f16x8*)&Bhs[team][bf][(ec * 64 + r) * 8] = cvt8_f16_rne(w8);          \
        }                                                                           \
    }

    STAGE(kbase, 0)
    for (int s = 0; s < 4; ++s) {
        __syncthreads();
        if (s + 1 < 4) STAGE(kbase + (s + 1) * 64, (s + 1) & 1)
        const int b = s & 1;
        f16x8 aH[2][2], bH[2][2];
#pragma unroll
        for (int mt = 0; mt < 2; ++mt) {
            const int row = wr * 32 + mt * 16 + c16;
            aH[mt][0] = *(const f16x8*)&Ahs[team][b][(q4 * 64 + row) * 8];
            aH[mt][1] = *(const f16x8*)&Ahs[team][b][((q4 + 4) * 64 + row) * 8];
        }
#pragma unroll
        for (int nt = 0; nt < 2; ++nt) {
            const int col = wc * 32 + nt * 16 + c16;
            bH[nt][0] = *(const f16x8*)&Bhs[team][b][(q4 * 64 + col) * 8];
            bH[nt][1] = *(const f16x8*)&Bhs[team][b][((q4 + 4) * 64 + col) * 8];
        }
#pragma unroll
        for (int mt = 0; mt < 2; ++mt)
#pragma unroll
            for (int nt = 0; nt < 2; ++nt) {
                acc[mt][nt] = __builtin_amdgcn_mfma_f32_16x16x32_f16(aH[mt][0], bH[nt][0], acc[mt][nt], 0, 0, 0);
                acc[mt][nt] = __builtin_amdgcn_mfma_f32_16x16x32_f16(aH[mt][1], bH[nt][1], acc[mt][nt], 0, 0, 0);
            }
    }
#undef STAGE

    if (team == 1) {
#pragma unroll
        for (int mt = 0; mt < 2; ++mt)
#pragma unroll
            for (int nt = 0; nt < 2; ++nt)
#pragma unroll
                for (int j = 0; j < 4; ++j) {
                    const int row = wr * 32 + mt * 16 + q4 * 4 + j;
                    const int col = wc * 32 + nt * 16 + c16;
                    accs[row][col] = acc[mt][nt][j];
                }
    }
    __syncthreads();
    if (team == 0) {
#pragma unroll
        for (int mt = 0; mt < 2; ++mt)
#pragma unroll
            for (int nt = 0; nt < 2; ++nt)
#pragma unroll
                for (int j = 0; j < 4; ++j) {
                    const int row = wr * 32 + mt * 16 + q4 * 4 + j;
                    const int col = wc * 32 + nt * 16 + c16;
                    const float v = acc[mt][nt][j] + accs[row][col];
                    const int n_row = m0 + row;
                    const int jcol = n0 + col;
                    const int b = n_row / SS, s2 = n_row % SS;
                    const int h = jcol >> 6, e = jcol & 63;
                    const int bh = b * HH + h;
                    if (p == 3) {
                        vhp[(bh * SS + s2) * HD + e] = v;
                    } else if (p == 0) {
                        qf16[(bh * SS + s2) * HD + e] = f16s(v * SCL);
                    } else {
                        short* dst = (p == 1) ? khf16 : lhf16;
                        dst[bh * KLPAD + (e >> 3) * (193 * 8) + s2 * 8 + (e & 7)] = f16s(v);
                    }
                }
    }
}

// ---------------------------------------------------------------------------
// MFMA rank-3 attention (dual-q core, pure-f16 staging) + fused outproj.
// Grid 512 = 16 bh x 32 qc (QCB=6) = 2 blocks/CU; 512 thr = 8 waves
// (2 lg x 4 kg). Dual-q (qa, qa+3): shared K-reads for both B-builds,
// shared A-reads for both MFMA sets, 12 MFMA + 6 independent exp chains
// per lt iteration. v_exp_f32 on the trans pipe. Fused Wout MFMA epilogue.
// NOTE (R23/R24): more blocks or more waves per CU both REGRESS -- the core
// is per-wave-overhead-bound, not occupancy-starved. This is the optimum
// of this decomposition under the 128-reg class / LDS box.
// ---------------------------------------------------------------------------
__global__ __launch_bounds__(512, 4) void attn3d_mfma_kernel(
    const short* __restrict__ qf16, const short* __restrict__ khf16,
    const short* __restrict__ lhf16, const float* __restrict__ vh,
    const float* __restrict__ Wout, float* __restrict__ out) {
    __shared__ short Kf16[8][193][8];       // [ec][k(+pad)][8] f16: 24.7 KB
    __shared__ short Lf16[8][193][8];       // [ec][l(+pad)][8] f16: 24.7 KB
    __shared__ short qpk[QCB][8][8];        // [q][ec][8] f16: 768 B
    __shared__ float partial[2][QCB][196];  // [lg][q][k(+pad)]: 9.4 KB
    __shared__ float Wt[QCB][192];          // 4.6 KB
    __shared__ float attd[16][72];          // attended, rows 6..15 zero: 4.5 KB
    __shared__ float zinv[QCB];

    const int blk = blockIdx.x;
    const int bh = blk >> 5, qc = blk & 31;
    const int t = threadIdx.x;
    const int lane = t & 63, w = t >> 6;
    const int lg = w >> 2, kg = w & 3;
    const int c = lane & 15, eh = lane >> 4;

    // ---- stage q rows (pre-scaled f16): 48 x 16B copies ----
    if (t < QCB * 8) {
        const int q = t >> 3, ecj = t & 7;
        *(f16x8*)&qpk[q][ecj][0] =
            *(const f16x8*)&qf16[(bh * SS + qc * QCB + q) * HD + ecj * 8];
    }
    // ---- stage K and L: pure 16B copies (layout matches LDS) ----
#pragma unroll
    for (int j = 0; j < 3; ++j) {
        const int cid = t + 512 * j;          // 0..1535
        const int ec = cid / 192, k2 = cid - ec * 192;
        const int off = ec * (193 * 8) + k2 * 8;
        *(f16x8*)&(((short*)Kf16)[off]) = *(const f16x8*)&khf16[bh * KLPAD + off];
        *(f16x8*)&(((short*)Lf16)[off]) = *(const f16x8*)&lhf16[bh * KLPAD + off];
    }
    __syncthreads();   // qpk, Kf16, Lf16 ready

    // ---- dual-q loop: 3 iterations, each handles (qa, qa+3) ----
    for (int qpi = 0; qpi < 3; ++qpi) {
        const int qa = (qpi + w) % 3;       // rotated per wave
        const int qb = qa + 3;
        const f16x8 qaf0 = *(const f16x8*)&qpk[qa][eh][0];
        const f16x8 qaf1 = *(const f16x8*)&qpk[qa][4 + eh][0];
        const f16x8 qbf0 = *(const f16x8*)&qpk[qb][eh][0];
        const f16x8 qbf1 = *(const f16x8*)&qpk[qb][4 + eh][0];
        f16x8 Ba[3][2], Bb[3][2];
#pragma unroll
        for (int kt = 0; kt < 3; ++kt) {
            const int col = kg * 48 + kt * 16 + c;
            const f16x8 Kf0 = *(const f16x8*)&Kf16[eh][col][0];
            const f16x8 Kf1 = *(const f16x8*)&Kf16[4 + eh][col][0];
            Ba[kt][0] = Kf0 * qaf0;
            Ba[kt][1] = Kf1 * qaf1;
            Bb[kt][0] = Kf0 * qbf0;
            Bb[kt][1] = Kf1 * qbf1;
        }
        float ra0 = 0.f, ra1 = 0.f, ra2 = 0.f;
        float rb0 = 0.f, rb1 = 0.f, rb2 = 0.f;
#pragma unroll
        for (int lt = 0; lt < 6; ++lt) {
            const int row = lg * 96 + lt * 16 + c;
            const f16x8 A0 = *(const f16x8*)&Lf16[eh][row][0];
            const f16x8 A1 = *(const f16x8*)&Lf16[4 + eh][row][0];
            f32x4 a0 = (f32x4){0.f, 0.f, 0.f, 0.f};
            f32x4 a1 = (f32x4){0.f, 0.f, 0.f, 0.f};
            f32x4 a2 = (f32x4){0.f, 0.f, 0.f, 0.f};
            f32x4 b0 = (f32x4){0.f, 0.f, 0.f, 0.f};
            f32x4 b1 = (f32x4){0.f, 0.f, 0.f, 0.f};
            f32x4 b2 = (f32x4){0.f, 0.f, 0.f, 0.f};
            a0 = __builtin_amdgcn_mfma_f32_16x16x32_f16(A0, Ba[0][0], a0, 0, 0, 0);
            a1 = __builtin_amdgcn_mfma_f32_16x16x32_f16(A0, Ba[1][0], a1, 0, 0, 0);
            a2 = __builtin_amdgcn_mfma_f32_16x16x32_f16(A0, Ba[2][0], a2, 0, 0, 0);
            b0 = __builtin_amdgcn_mfma_f32_16x16x32_f16(A0, Bb[0][0], b0, 0, 0, 0);
            b1 = __builtin_amdgcn_mfma_f32_16x16x32_f16(A0, Bb[1][0], b1, 0, 0, 0);
            b2 = __builtin_amdgcn_mfma_f32_16x16x32_f16(A0, Bb[2][0], b2, 0, 0, 0);
            a0 = __builtin_amdgcn_mfma_f32_16x16x32_f16(A1, Ba[0][1], a0, 0, 0, 0);
            a1 = __builtin_amdgcn_mfma_f32_16x16x32_f16(A1, Ba[1][1], a1, 0, 0, 0);
            a2 = __builtin_amdgcn_mfma_f32_16x16x32_f16(A1, Ba[2][1], a2, 0, 0, 0);
            b0 = __builtin_amdgcn_mfma_f32_16x16x32_f16(A1, Bb[0][1], b0, 0, 0, 0);
            b1 = __builtin_amdgcn_mfma_f32_16x16x32_f16(A1, Bb[1][1], b1, 0, 0, 0);
            b2 = __builtin_amdgcn_mfma_f32_16x16x32_f16(A1, Bb[2][1], b2, 0, 0, 0);
            ra0 += (__builtin_amdgcn_exp2f(a0[0]) + __builtin_amdgcn_exp2f(a0[1])) +
                   (__builtin_amdgcn_exp2f(a0[2]) + __builtin_amdgcn_exp2f(a0[3]));
            ra1 += (__builtin_amdgcn_exp2f(a1[0]) + __builtin_amdgcn_exp2f(a1[1])) +
                   (__builtin_amdgcn_exp2f(a1[2]) + __builtin_amdgcn_exp2f(a1[3]));
            ra2 += (__builtin_amdgcn_exp2f(a2[0]) + __builtin_amdgcn_exp2f(a2[1])) +
                   (__builtin_amdgcn_exp2f(a2[2]) + __builtin_amdgcn_exp2f(a2[3]));
            rb0 += (__builtin_amdgcn_exp2f(b0[0]) + __builtin_amdgcn_exp2f(b0[1])) +
                   (__builtin_amdgcn_exp2f(b0[2]) + __builtin_amdgcn_exp2f(b0[3]));
            rb1 += (__builtin_amdgcn_exp2f(b1[0]) + __builtin_amdgcn_exp2f(b1[1])) +
                   (__builtin_amdgcn_exp2f(b1[2]) + __builtin_amdgcn_exp2f(b1[3]));
            rb2 += (__builtin_amdgcn_exp2f(b2[0]) + __builtin_amdgcn_exp2f(b2[1])) +
                   (__builtin_amdgcn_exp2f(b2[2]) + __builtin_amdgcn_exp2f(b2[3]));
        }
        // 6 independent shuffle chains (ILP-overlapped)
        ra0 += __shfl_xor(ra0, 16, 64);
        ra1 += __shfl_xor(ra1, 16, 64);
        ra2 += __shfl_xor(ra2, 16, 64);
        rb0 += __shfl_xor(rb0, 16, 64);
        rb1 += __shfl_xor(rb1, 16, 64);
        rb2 += __shfl_xor(rb2, 16, 64);
        ra0 += __shfl_xor(ra0, 32, 64);
        ra1 += __shfl_xor(ra1, 32, 64);
        ra2 += __shfl_xor(ra2, 32, 64);
        rb0 += __shfl_xor(rb0, 32, 64);
        rb1 += __shfl_xor(rb1, 32, 64);
        rb2 += __shfl_xor(rb2, 32, 64);
        if (eh == 0) {
            partial[lg][qa][kg * 48 + 0 * 16 + c] = ra0;
            partial[lg][qa][kg * 48 + 1 * 16 + c] = ra1;
            partial[lg][qa][kg * 48 + 2 * 16 + c] = ra2;
            partial[lg][qb][kg * 48 + 0 * 16 + c] = rb0;
            partial[lg][qb][kg * 48 + 1 * 16 + c] = rb1;
            partial[lg][qb][kg * 48 + 2 * 16 + c] = rb2;
        }
    }
    __syncthreads();   // all partials written

    // combine lg partials
    for (int id = t; id < QCB * 192; id += 512) {
        const int q = id / 192, k = id - q * 192;
        Wt[q][k] = partial[0][q][k] + partial[1][q][k];
    }
    // zero attd (incl. rows 6..15 used as zero A-rows in the epilogue MFMA)
    for (int id = t; id < 16 * 72; id += 512) ((float*)attd)[id] = 0.f;
    __syncthreads();

    // Z per q (wave w handles q = w)
    if (w < QCB) {
        const int q = w;
        float z = Wt[q][lane] + Wt[q][lane + 64] + Wt[q][lane + 128];
#pragma unroll
        for (int off = 32; off >= 1; off >>= 1) z += __shfl_xor(z, off, 64);
        if (lane == 0) zinv[q] = 1.f / z;
    }
    __syncthreads();

    // attended -> attd LDS: attd[q][d] = zinv * sum_k Wt[q][k] * vh[k,d]
    if (t < QCB * 64) {
        const int q = t >> 6, d = t & 63;
        const float* vp = vh + bh * SS * HD + d;
        float sum = 0.f;
        for (int k0 = 0; k0 < SS; k0 += 8) {
            float v8[8];
#pragma unroll
            for (int j = 0; j < 8; ++j) v8[j] = vp[(k0 + j) * HD];
#pragma unroll
            for (int j = 0; j < 8; ++j) sum = fmaf(Wt[q][k0 + j], v8[j], sum);
        }
        attd[q][d] = sum * zinv[q];
    }
    __syncthreads();

    // ---- fused output projection: out[q,:] += attd . Wout[:, h*64:+64]^T ----
    const int b = bh >> 3, h = bh & 7;
    f16x8 Ae0, Ae1;
    {
        float a8[8];
        *(f32x4*)&a8[0] = *(const f32x4*)&attd[c][eh * 8];
        *(f32x4*)&a8[4] = *(const f32x4*)&attd[c][eh * 8 + 4];
        Ae0 = cvt8_f16_rne(a8);
        *(f32x4*)&a8[0] = *(const f32x4*)&attd[c][32 + eh * 8];
        *(f32x4*)&a8[4] = *(const f32x4*)&attd[c][32 + eh * 8 + 4];
        Ae1 = cvt8_f16_rne(a8);
    }
#pragma unroll
    for (int jt = 0; jt < 4; ++jt) {
        const int j = (w * 4 + jt) * 16 + c;
        const float* wp = &Wout[j * DD + h * HD];
        float b8[8];
        *(f32x4*)&b8[0] = *(const f32x4*)&wp[eh * 8];
        *(f32x4*)&b8[4] = *(const f32x4*)&wp[eh * 8 + 4];
        const f16x8 B0 = cvt8_f16_rne(b8);
        *(f32x4*)&b8[0] = *(const f32x4*)&wp[32 + eh * 8];
        *(f32x4*)&b8[4] = *(const f32x4*)&wp[32 + eh * 8 + 4];
        const f16x8 B1 = cvt8_f16_rne(b8);
        f32x4 oc = (f32x4){0.f, 0.f, 0.f, 0.f};
        oc = __builtin_amdgcn_mfma_f32_16x16x32_f16(Ae0, B0, oc, 0, 0, 0);
        oc = __builtin_amdgcn_mfma_f32_16x16x32_f16(Ae1, B1, oc, 0, 0, 0);
#pragma unroll
        for (int jj = 0; jj < 4; ++jj) {
            const int q = eh * 4 + jj;
            if (q < QCB)
                atomicAdd(&out[(b * SS + qc * QCB + q) * DD + (w * 4 + jt) * 16 + c], oc[jj]);
        }
    }
}

extern "C" void kernel_launch(void* const* d_in, const int* in_sizes, int n_in,
                              void* d_out, int out_size, void* d_ws, size_t ws_size,
                              hipStream_t stream) {
    (void)in_sizes; (void)n_in; (void)out_size; (void)ws_size;
    const float* q    = (const float*)d_in[0];
    const float* k    = (const float*)d_in[1];
    const float* l    = (const float*)d_in[2];
    const float* v    = (const float*)d_in[3];
    const float* Wq   = (const float*)d_in[4];
    const float* Wk   = (const float*)d_in[5];
    const float* Wv   = (const float*)d_in[6];
    const float* Wout = (const float*)d_in[7];
    float* out = (float*)d_out;

    float* ws    = (float*)d_ws;
    float* vhp   = ws;                                   // PROJ_N f32
    short* qf16  = (short*)(ws + PROJ_N);                // PROJ_N f16
    short* khf16 = qf16 + PROJ_N;                        // 16*KLPAD f16 (padded)
    short* lhf16 = khf16 + 16 * KLPAD;                   // 16*KLPAD f16

    // projections (split-K teams, f16 outputs pre-laid-out) + out-zero prologue
    proj4_kernel<<<dim3(384 / 64, 512 / 64, 4), 512, 0, stream>>>(
        q, k, l, v, Wq, Wk, Wv, vhp, qf16, khf16, lhf16, out);
    // rank-3 attention + fused output projection
    attn3d_mfma_kernel<<<dim3(16 * NQC), 512, 0, stream>>>(
        qf16, khf16, lhf16, vhp, Wout, out);
}